// Round 1
// baseline (3299.677 us; speedup 1.0000x reference)
//
#include <hip/hip_runtime.h>
#include <math.h>

#define NC 8192
#define ID 512
#define HD 1024
#define OD 512
#define ED 128
#define NF 8
#define FS (NC/NF)   /* 1024 */
#define DC (FS/4)    /* 256 */

__device__ __forceinline__ float sigmf(float x){ return 1.0f/(1.0f+__expf(-x)); }

// ---------------------------------------------------------------------------
// K1: decohere features: feat[:, :HD] = softmax(rho_diag + noise_diag*g*0.1)
//     feat[:, HD:]  = |rho_offdiag| * (1-g)
// one block per row, 256 threads
__global__ __launch_bounds__(256) void k_feat(
    const float* __restrict__ rho_diag, const float* __restrict__ noise_diag,
    const float* __restrict__ rho_off,  const float* __restrict__ gamma,
    float* __restrict__ feat)
{
  int row = blockIdx.x;
  int t = threadIdx.x;
  float g = 1.0f/(1.0f+__expf(-gamma[0]));
  const float* rd = rho_diag  + (size_t)row*HD;
  const float* nd = noise_diag+ (size_t)row*HD;
  const float* ro = rho_off   + (size_t)row*HD;
  float* f0 = feat + (size_t)row*(2*HD);

  float v[4];
  float mx = -1e30f;
  for (int i=0;i<4;i++){ int j=t+i*256; v[i] = rd[j] + nd[j]*g*0.1f; mx = fmaxf(mx, v[i]); }
  __shared__ float red[256];
  red[t]=mx; __syncthreads();
  for(int s=128;s>0;s>>=1){ if(t<s) red[t]=fmaxf(red[t],red[t+s]); __syncthreads(); }
  mx = red[0]; __syncthreads();
  float sm=0.0f;
  for(int i=0;i<4;i++){ v[i]=__expf(v[i]-mx); sm+=v[i]; }
  red[t]=sm; __syncthreads();
  for(int s=128;s>0;s>>=1){ if(t<s) red[t]+=red[t+s]; __syncthreads(); }
  float inv = 1.0f/red[0];
  float om_g = 1.0f - g;
  for(int i=0;i<4;i++){ int j=t+i*256; f0[j] = v[i]*inv; f0[HD+j] = fabsf(ro[j])*om_g; }
}

// ---------------------------------------------------------------------------
// Generic fp32 tiled GEMM: C[M,N] = A[M,K] @ W[N,K]^T  (+ epilogue)
// W row n starts at Wp + n*ldw + wofs.
// mode 0: C = e0[m*N+n] + 0.1*(acc + e1[n])          (h = hiddens + 0.1*inj)
// mode 1: C = relu(acc + e0[n])                       (engine hidden, bias=xpart)
// mode 2: C = acc + e0[n] + e1[m]*e2[n]               (gi with tension rank-1 + bih)
// All dims divisible by tile (64/16) for our shapes.
__global__ __launch_bounds__(256) void k_gemm(
    const float* __restrict__ A, int lda,
    const float* __restrict__ Wp, int ldw, int wofs,
    int M, int N, int K,
    float* __restrict__ C, int ldc, int mode,
    const float* __restrict__ e0, const float* __restrict__ e1,
    const float* __restrict__ e2)
{
  __shared__ float As[16][65];
  __shared__ float Ws[16][65];
  int t = threadIdx.x;
  int m0 = blockIdx.y*64, n0 = blockIdx.x*64;
  int tm = t>>4, tn = t&15;
  float acc[4][4] = {};
  for (int k0=0;k0<K;k0+=16){
    for (int i=0;i<4;i++){
      int idx = t + i*256;
      int mm = idx>>4, kk = idx&15;
      As[kk][mm] = A[(size_t)(m0+mm)*lda + k0+kk];
      Ws[kk][mm] = Wp[(size_t)(n0+mm)*ldw + wofs + k0+kk];
    }
    __syncthreads();
    for (int kk=0;kk<16;kk++){
      float ra[4], rw[4];
      for (int i=0;i<4;i++) ra[i]=As[kk][tm*4+i];
      for (int j=0;j<4;j++) rw[j]=Ws[kk][tn*4+j];
      for (int i=0;i<4;i++)
        for (int j=0;j<4;j++) acc[i][j] += ra[i]*rw[j];
    }
    __syncthreads();
  }
  for (int i=0;i<4;i++){
    int m = m0 + tm*4 + i;
    for (int j=0;j<4;j++){
      int n = n0 + tn*4 + j;
      float v = acc[i][j];
      if (mode==0)      v = e0[(size_t)m*N + n] + 0.1f*(v + e1[n]);
      else if (mode==1) v = fmaxf(v + e0[n], 0.0f);
      else if (mode==2) v = v + e0[n] + e1[m]*e2[n];
      C[(size_t)m*ldc + n] = v;
    }
  }
}

// ---------------------------------------------------------------------------
// K3: x-part of the engine MLPs + strided copy of Wih last column.
// block 0: xa[n] = a_b1[n] + sum_k x[k]*a_W1[n,k<512]
// block 1: xg[n] = ...
// block 2: wlast[n] = gru_Wih[n*513 + 512]   (n < 3072)
__global__ __launch_bounds__(128) void k_xpart(
    const float* __restrict__ x,
    const float* __restrict__ aW1, const float* __restrict__ ab1,
    const float* __restrict__ gW1, const float* __restrict__ gb1,
    const float* __restrict__ Wih,
    float* __restrict__ xa, float* __restrict__ xg, float* __restrict__ wlast)
{
  int t = threadIdx.x;
  if (blockIdx.x == 2){
    for (int n=t; n<3*HD; n+=128) wlast[n] = Wih[(size_t)n*(OD+1) + OD];
    return;
  }
  const float* W = blockIdx.x ? gW1 : aW1;
  const float* b = blockIdx.x ? gb1 : ab1;
  float* o       = blockIdx.x ? xg  : xa;
  float s = b[t];
  const float* wr = W + (size_t)t*(ID+HD);
  for (int k=0;k<ID;k++) s += x[k]*wr[k];
  o[t] = s;
}

// ---------------------------------------------------------------------------
// K5: out = ea@a_W2^T - eg@g_W2^T + (a_b2 - g_b2);  tension = mean(out^2)
// one block per row m, 128 threads
__global__ __launch_bounds__(128) void k_out(
    const float* __restrict__ ea, const float* __restrict__ eg,
    const float* __restrict__ aW2, const float* __restrict__ ab2,
    const float* __restrict__ gW2, const float* __restrict__ gb2,
    float* __restrict__ outp, float* __restrict__ tens)
{
  int m = blockIdx.x, t = threadIdx.x;
  __shared__ float sa[ED], sg[ED];
  sa[t] = ea[(size_t)m*ED + t];
  sg[t] = eg[(size_t)m*ED + t];
  __syncthreads();
  float sq = 0.0f;
  for (int rep=0; rep<4; rep++){
    int n = t + rep*128;
    float acc = ab2[n] - gb2[n];
    const float* wa = aW2 + (size_t)n*ED;
    const float* wg = gW2 + (size_t)n*ED;
    for (int k=0;k<ED;k++) acc += sa[k]*wa[k] - sg[k]*wg[k];
    outp[(size_t)m*OD + n] = acc;
    sq += acc*acc;
  }
  __shared__ float red[128];
  red[t]=sq; __syncthreads();
  for (int s=64;s>0;s>>=1){ if(t<s) red[t]+=red[t+s]; __syncthreads(); }
  if (t==0) tens[m] = red[0] * (1.0f/OD);
}

// ---------------------------------------------------------------------------
// K7: gh GEMM (h @ Whh^T over 3 gate chunks) fused with GRU combine.
// writes new_h directly (pre faction sync) to d_out+512
__global__ __launch_bounds__(256) void k_gru(
    const float* __restrict__ h, const float* __restrict__ Whh,
    const float* __restrict__ bhh, const float* __restrict__ gi,
    float* __restrict__ newh)
{
  __shared__ float As[16][65];
  __shared__ float Wr[16][65], Wz[16][65], Wn[16][65];
  int t = threadIdx.x;
  int m0 = blockIdx.y*64, n0 = blockIdx.x*64;
  int tm = t>>4, tn = t&15;
  float ar[4][4]={}, az[4][4]={}, an[4][4]={};
  for (int k0=0;k0<HD;k0+=16){
    for (int i=0;i<4;i++){
      int idx = t + i*256;
      int mm = idx>>4, kk = idx&15;
      As[kk][mm] = h  [(size_t)(m0+mm)*HD + k0+kk];
      Wr[kk][mm] = Whh[(size_t)(n0+mm)*HD + k0+kk];
      Wz[kk][mm] = Whh[(size_t)(HD   + n0+mm)*HD + k0+kk];
      Wn[kk][mm] = Whh[(size_t)(2*HD + n0+mm)*HD + k0+kk];
    }
    __syncthreads();
    for (int kk=0;kk<16;kk++){
      float ra[4];
      for (int i=0;i<4;i++) ra[i]=As[kk][tm*4+i];
      for (int j=0;j<4;j++){
        float wr=Wr[kk][tn*4+j], wz=Wz[kk][tn*4+j], wn=Wn[kk][tn*4+j];
        for (int i=0;i<4;i++){
          ar[i][j] += ra[i]*wr;
          az[i][j] += ra[i]*wz;
          an[i][j] += ra[i]*wn;
        }
      }
    }
    __syncthreads();
  }
  for (int i=0;i<4;i++){
    int m = m0 + tm*4 + i;
    for (int j=0;j<4;j++){
      int n = n0 + tn*4 + j;
      float i_r = gi[(size_t)m*(3*HD) + n];
      float i_z = gi[(size_t)m*(3*HD) + HD + n];
      float i_n = gi[(size_t)m*(3*HD) + 2*HD + n];
      float r  = sigmf(i_r + ar[i][j] + bhh[n]);
      float z  = sigmf(i_z + az[i][j] + bhh[HD+n]);
      float nn = tanhf(i_n + r*(an[i][j] + bhh[2*HD+n]));
      float hv = h[(size_t)m*HD + n];
      newh[(size_t)m*HD + n] = (1.0f-z)*nn + z*hv;
    }
  }
}

// ---------------------------------------------------------------------------
// K8: per-faction mean over FS cells. grid (NF, HD/256), block 256
__global__ __launch_bounds__(256) void k_fmean(
    const float* __restrict__ newh, float* __restrict__ fmean)
{
  int f = blockIdx.x;
  int j = blockIdx.y*256 + threadIdx.x;
  const float* base = newh + (size_t)f*FS*HD + j;
  float s = 0.0f;
  for (int c=0;c<FS;c++) s += base[(size_t)c*HD];
  fmean[f*HD + j] = s * (1.0f/FS);
}

// ---------------------------------------------------------------------------
// K9: faction sync + debate, in place on new_h.
// post-sync per-faction mean == pre-sync mean, so glob = mean_f fmean[f].
__global__ __launch_bounds__(256) void k_sync(
    float* __restrict__ newh, const float* __restrict__ fmean,
    const int* __restrict__ step)
{
  size_t idx = (size_t)blockIdx.x*256 + threadIdx.x;   // NC*HD total
  int cell = (int)(idx / HD);
  int j    = (int)(idx % HD);
  int f = cell / FS, c = cell % FS;
  float v = newh[idx];
  v = 0.85f*v + 0.15f*fmean[f*HD + j];
  if (step[0] > 5 && c < DC){
    float glob = 0.0f;
    for (int ff=0; ff<NF; ff++) glob += fmean[ff*HD + j];
    glob *= (1.0f/NF);
    v = 0.85f*v + 0.15f*glob;
  }
  newh[idx] = v;
}

// ---------------------------------------------------------------------------
// K10a: softmax stats over tension[NC]
__global__ __launch_bounds__(1024) void k_wstats(
    const float* __restrict__ tens, float* __restrict__ stats)
{
  int t = threadIdx.x;
  float mx = -1e30f;
  for (int i=t;i<NC;i+=1024) mx = fmaxf(mx, tens[i]);
  __shared__ float red[1024];
  red[t]=mx; __syncthreads();
  for(int s=512;s>0;s>>=1){ if(t<s) red[t]=fmaxf(red[t],red[t+s]); __syncthreads(); }
  mx = red[0]; __syncthreads();
  float sm=0.0f;
  for (int i=t;i<NC;i+=1024) sm += __expf(tens[i]-mx);
  red[t]=sm; __syncthreads();
  for(int s=512;s>0;s>>=1){ if(t<s) red[t]+=red[t+s]; __syncthreads(); }
  if (t==0){ stats[0]=mx; stats[1]=red[0]; }
}

// K10b: normalized weights
__global__ __launch_bounds__(256) void k_wnorm(
    const float* __restrict__ tens, const float* __restrict__ stats,
    float* __restrict__ w)
{
  int m = blockIdx.x*256 + threadIdx.x;
  w[m] = __expf(tens[m]-stats[0]) * (1.0f/stats[1]);
}

// K10c: combined[n] = sum_m w[m]*out[m,n]; one block per n
__global__ __launch_bounds__(256) void k_combined(
    const float* __restrict__ outp, const float* __restrict__ w,
    float* __restrict__ comb)
{
  int n = blockIdx.x, t = threadIdx.x;
  float s = 0.0f;
  for (int m=t; m<NC; m+=256) s += w[m]*outp[(size_t)m*OD + n];
  __shared__ float red[256];
  red[t]=s; __syncthreads();
  for (int sx=128;sx>0;sx>>=1){ if(t<sx) red[t]+=red[t+sx]; __syncthreads(); }
  if (t==0) comb[n] = red[0];
}

// K11: pred[i] = head_b[i] + sum_k comb[k]*head_W[i,k]; one block per i
__global__ __launch_bounds__(128) void k_pred(
    const float* __restrict__ comb, const float* __restrict__ headW,
    const float* __restrict__ headb, float* __restrict__ pred)
{
  int i = blockIdx.x, t = threadIdx.x;
  float s = 0.0f;
  const float* wr = headW + (size_t)i*OD;
  for (int k=t;k<OD;k+=128) s += comb[k]*wr[k];
  __shared__ float red[128];
  red[t]=s; __syncthreads();
  for (int sx=64;sx>0;sx>>=1){ if(t<sx) red[t]+=red[t+sx]; __syncthreads(); }
  if (t==0) pred[i] = red[0] + headb[i];
}

// ---------------------------------------------------------------------------
extern "C" void kernel_launch(void* const* d_in, const int* in_sizes, int n_in,
                              void* d_out, int out_size, void* d_ws, size_t ws_size,
                              hipStream_t stream)
{
  const float* x        = (const float*)d_in[0];
  const float* rho_diag = (const float*)d_in[1];
  const float* rho_off  = (const float*)d_in[2];
  const float* hiddens  = (const float*)d_in[3];
  const float* gamma    = (const float*)d_in[4];
  const float* proj_W   = (const float*)d_in[5];
  const float* proj_b   = (const float*)d_in[6];
  const float* a_W1     = (const float*)d_in[7];
  const float* a_b1     = (const float*)d_in[8];
  const float* a_W2     = (const float*)d_in[9];
  const float* a_b2     = (const float*)d_in[10];
  const float* g_W1     = (const float*)d_in[11];
  const float* g_b1     = (const float*)d_in[12];
  const float* g_W2     = (const float*)d_in[13];
  const float* g_b2     = (const float*)d_in[14];
  const float* gru_Wih  = (const float*)d_in[15];
  const float* gru_bih  = (const float*)d_in[16];
  const float* gru_Whh  = (const float*)d_in[17];
  const float* gru_bhh  = (const float*)d_in[18];
  const float* head_W   = (const float*)d_in[19];
  const float* head_b   = (const float*)d_in[20];
  const float* noise_d  = (const float*)d_in[21];
  const int*   step     = (const int*)d_in[23];

  float* pred = (float*)d_out;                  // [512]
  float* newh = (float*)d_out + ID;             // [NC*HD]

  char* ws = (char*)d_ws;
  const size_t MB = 1024*1024;
  // region A (96MB): feat [NC,2HD] (64MB) + ea/eg (4MB each); later reused as gi [NC,3HD]
  float* feat = (float*)(ws + 0);
  float* ea   = (float*)(ws + 64*MB);
  float* eg   = (float*)(ws + 68*MB);
  float* gi   = (float*)(ws + 0);
  float* h    = (float*)(ws + 96*MB);           // [NC,HD] 32MB
  float* outp = (float*)(ws + 128*MB);          // [NC,OD] 16MB
  char*  sm   = ws + 144*MB;
  float* tens  = (float*)(sm + 0);              // [NC]
  float* xa    = (float*)(sm + 64*1024);        // [ED]
  float* xg    = (float*)(sm + 65*1024);        // [ED]
  float* wlast = (float*)(sm + 128*1024);       // [3HD]
  float* fmean = (float*)(sm + 192*1024);       // [NF*HD]
  float* stats = (float*)(sm + 256*1024);       // [2]
  float* wts   = (float*)(sm + 320*1024);       // [NC]
  float* comb  = (float*)(sm + 384*1024);       // [OD]

  dim3 blk(256);

  // 1. feat
  k_feat<<<dim3(NC), blk, 0, stream>>>(rho_diag, noise_d, rho_off, gamma, feat);
  // 2. inj GEMM -> h
  k_gemm<<<dim3(HD/64, NC/64), blk, 0, stream>>>(
      feat, 2*HD, proj_W, 2*HD, 0, NC, HD, 2*HD, h, HD, 0, hiddens, proj_b, nullptr);
  // 3. x-part biases + wlast copy
  k_xpart<<<dim3(3), dim3(128), 0, stream>>>(x, a_W1, a_b1, g_W1, g_b1, gru_Wih, xa, xg, wlast);
  // 4. engine hidden GEMMs (K over h only)
  k_gemm<<<dim3(ED/64, NC/64), blk, 0, stream>>>(
      h, HD, a_W1, ID+HD, ID, NC, ED, HD, ea, ED, 1, xa, nullptr, nullptr);
  k_gemm<<<dim3(ED/64, NC/64), blk, 0, stream>>>(
      h, HD, g_W1, ID+HD, ID, NC, ED, HD, eg, ED, 1, xg, nullptr, nullptr);
  // 5. out + tension
  k_out<<<dim3(NC), dim3(128), 0, stream>>>(ea, eg, a_W2, a_b2, g_W2, g_b2, outp, tens);
  // 6. gi GEMM (overwrites region A; feat/ea/eg dead now)
  k_gemm<<<dim3(3*HD/64, NC/64), blk, 0, stream>>>(
      outp, OD, gru_Wih, OD+1, 0, NC, 3*HD, OD, gi, 3*HD, 2, gru_bih, tens, wlast);
  // 7. gh GEMM + GRU fused -> new_h (pre-sync)
  k_gru<<<dim3(HD/64, NC/64), blk, 0, stream>>>(h, gru_Whh, gru_bhh, gi, newh);
  // 8. faction means
  k_fmean<<<dim3(NF, HD/256), blk, 0, stream>>>(newh, fmean);
  // 9. sync + debate in place
  k_sync<<<dim3((NC*HD)/256), blk, 0, stream>>>(newh, fmean, step);
  // 10. tension softmax -> weights -> combined
  k_wstats<<<dim3(1), dim3(1024), 0, stream>>>(tens, stats);
  k_wnorm<<<dim3(NC/256), blk, 0, stream>>>(tens, stats, wts);
  k_combined<<<dim3(OD), blk, 0, stream>>>(outp, wts, comb);
  // 11. pred head
  k_pred<<<dim3(ID), dim3(128), 0, stream>>>(comb, head_W, head_b, pred);
}

// Round 2
// 623.551 us; speedup vs baseline: 5.2918x; 5.2918x over previous
//
#include <hip/hip_runtime.h>
#include <math.h>

#define NC 8192
#define ID 512
#define HD 1024
#define OD 512
#define ED 128
#define NF 8
#define FS (NC/NF)   /* 1024 */
#define DC (FS/4)    /* 256 */

typedef __bf16 bf16x8 __attribute__((ext_vector_type(8)));
typedef float  f32x4  __attribute__((ext_vector_type(4)));

__device__ __forceinline__ float sigmf(float x){ return 1.0f/(1.0f+__expf(-x)); }

__device__ __forceinline__ unsigned short f2bf(float f){
  union { float f; unsigned u; } v; v.f = f;
  unsigned r = v.u + 0x7FFFu + ((v.u >> 16) & 1u);
  return (unsigned short)(r >> 16);
}
__device__ __forceinline__ float bf2f(unsigned short b){
  union { unsigned u; float f; } v; v.u = ((unsigned)b) << 16;
  return v.f;
}
__device__ __forceinline__ void gload16(const void* g, void* l){
  __builtin_amdgcn_global_load_lds(
      (const __attribute__((address_space(1))) unsigned int*)g,
      (__attribute__((address_space(3))) unsigned int*)l, 16, 0, 0);
}

// ---------------------------------------------------------------------------
// weight fp32 -> bf16 strided converter (scalar loads: src_ld may be odd, e.g. 513)
__global__ __launch_bounds__(256) void k_conv(
    const float* __restrict__ src, unsigned short* __restrict__ dst,
    int rows, int cols, int sld, int sofs, int dld, float scale)
{
  int i = blockIdx.x*256 + threadIdx.x;          // group of 4 elements
  int total = rows*cols/4;
  if (i >= total) return;
  int r = (i*4)/cols, c = (i*4)%cols;
  const float* s = src + (size_t)r*sld + sofs + c;
  unsigned long long pack = 0;
  for (int q=0;q<4;q++)
    pack |= (unsigned long long)f2bf(s[q]*scale) << (16*q);
  *reinterpret_cast<unsigned long long*>(&dst[(size_t)r*dld + c]) = pack;
}

// ---------------------------------------------------------------------------
// K1: decohere features -> bf16 feat[NC][2HD]
__global__ __launch_bounds__(256) void k_feat(
    const float* __restrict__ rho_diag, const float* __restrict__ noise_diag,
    const float* __restrict__ rho_off,  const float* __restrict__ gamma,
    unsigned short* __restrict__ featb)
{
  int row = blockIdx.x;
  int t = threadIdx.x;
  float g = 1.0f/(1.0f+__expf(-gamma[0]));
  const float* rd = rho_diag  + (size_t)row*HD;
  const float* nd = noise_diag+ (size_t)row*HD;
  const float* ro = rho_off   + (size_t)row*HD;
  unsigned short* f0 = featb + (size_t)row*(2*HD);

  float v[4];
  float mx = -1e30f;
  for (int i=0;i<4;i++){ int j=t+i*256; v[i] = rd[j] + nd[j]*g*0.1f; mx = fmaxf(mx, v[i]); }
  __shared__ float red[256];
  red[t]=mx; __syncthreads();
  for(int s=128;s>0;s>>=1){ if(t<s) red[t]=fmaxf(red[t],red[t+s]); __syncthreads(); }
  mx = red[0]; __syncthreads();
  float sm=0.0f;
  for(int i=0;i<4;i++){ v[i]=__expf(v[i]-mx); sm+=v[i]; }
  red[t]=sm; __syncthreads();
  for(int s=128;s>0;s>>=1){ if(t<s) red[t]+=red[t+s]; __syncthreads(); }
  float inv = 1.0f/red[0];
  float om_g = 1.0f - g;
  for(int i=0;i<4;i++){
    int j=t+i*256;
    f0[j]     = f2bf(v[i]*inv);
    f0[HD+j]  = f2bf(fabsf(ro[j])*om_g);
  }
}

// ---------------------------------------------------------------------------
// MFMA bf16 GEMM: C[M,N] = A[M,K] @ W[N,K]^T, 128x128 tile, BK=32, 4 waves.
// MODE 0: v = e0[m*N+n] + 0.1*(acc + e1[n]); write Cf + Cb     (inj -> h)
// MODE 1: v = relu(acc + e0[n]);            write Cb           (engine hidden)
// MODE 2: v = acc + e0[n];                  write Cf + Cb      (out)
// MODE 3: v = acc;                          write Cb           (gh)
// MODE 4: v = acc + e0[n] + e1[m]*e2[n];    write Cb           (gi)
template<int MODE>
__global__ __launch_bounds__(256) void k_mgemm(
    const unsigned short* __restrict__ A,   // [M][K] bf16
    const unsigned short* __restrict__ W,   // [N][K] bf16
    int K, int N,
    float* __restrict__ Cf, unsigned short* __restrict__ Cb, int ldc,
    const float* __restrict__ e0, const float* __restrict__ e1,
    const float* __restrict__ e2)
{
  __shared__ __attribute__((aligned(16))) unsigned short Asb[128*32];
  __shared__ __attribute__((aligned(16))) unsigned short Bsb[128*32];
  const int t = threadIdx.x;
  const int lane = t & 63, wid = t >> 6;
  const int wr = wid >> 1, wc = wid & 1;
  const int m0 = blockIdx.y * 128, n0 = blockIdx.x * 128;

  const int srow = lane >> 2;          // 0..15
  const int skch = (lane & 3) * 8;     // k chunk of 8 bf16 (16B)
  const int fr = lane & 15, fk = (lane >> 4) * 8;

  f32x4 acc[4][4] = {};
  for (int k0 = 0; k0 < K; k0 += 32) {
    for (int q = 0; q < 2; ++q) {
      int r = wid*32 + q*16 + srow;
      gload16(A + (size_t)(m0 + r)*K + k0 + skch, &Asb[(wid*32 + q*16)*32]);
      gload16(W + (size_t)(n0 + r)*K + k0 + skch, &Bsb[(wid*32 + q*16)*32]);
    }
    __syncthreads();
    bf16x8 af[4], bfr[4];
    for (int i = 0; i < 4; ++i)
      af[i]  = *reinterpret_cast<const bf16x8*>(&Asb[(wr*64 + i*16 + fr)*32 + fk]);
    for (int j = 0; j < 4; ++j)
      bfr[j] = *reinterpret_cast<const bf16x8*>(&Bsb[(wc*64 + j*16 + fr)*32 + fk]);
    for (int i = 0; i < 4; ++i)
      for (int j = 0; j < 4; ++j)
        acc[i][j] = __builtin_amdgcn_mfma_f32_16x16x32_bf16(af[i], bfr[j], acc[i][j], 0, 0, 0);
    __syncthreads();
  }
  const int cr = (lane >> 4) * 4;
  const int cc = lane & 15;
  for (int i = 0; i < 4; ++i){
    for (int j = 0; j < 4; ++j){
      for (int r = 0; r < 4; ++r){
        int m = m0 + wr*64 + i*16 + cr + r;
        int n = n0 + wc*64 + j*16 + cc;
        float v = acc[i][j][r];
        if (MODE == 0)      v = e0[(size_t)m*N + n] + 0.1f*(v + e1[n]);
        else if (MODE == 1) v = fmaxf(v + e0[n], 0.0f);
        else if (MODE == 2) v = v + e0[n];
        else if (MODE == 4) v = v + e0[n] + e1[m]*e2[n];
        size_t o = (size_t)m*ldc + n;
        if (MODE == 0 || MODE == 2) Cf[o] = v;
        Cb[o] = f2bf(v);
      }
    }
  }
}

// ---------------------------------------------------------------------------
// K3: x-part of engine MLPs (xcat[0:128]=a, [128:256]=g), wlast, b2diff
__global__ __launch_bounds__(128) void k_xpart(
    const float* __restrict__ x,
    const float* __restrict__ aW1, const float* __restrict__ ab1,
    const float* __restrict__ gW1, const float* __restrict__ gb1,
    const float* __restrict__ Wih,
    const float* __restrict__ ab2, const float* __restrict__ gb2,
    float* __restrict__ xcat, float* __restrict__ wlast, float* __restrict__ b2diff)
{
  int t = threadIdx.x;
  if (blockIdx.x == 2){
    for (int n=t; n<3*HD; n+=128) wlast[n] = Wih[(size_t)n*(OD+1) + OD];
    for (int n=t; n<OD;   n+=128) b2diff[n] = ab2[n] - gb2[n];
    return;
  }
  const float* W = blockIdx.x ? gW1 : aW1;
  const float* b = blockIdx.x ? gb1 : ab1;
  float s = b[t];
  const float* wr = W + (size_t)t*(ID+HD);
  for (int k=0;k<ID;k++) s += x[k]*wr[k];
  xcat[blockIdx.x*ED + t] = s;
}

// ---------------------------------------------------------------------------
// tension[m] = mean(out[m,:]^2)
__global__ __launch_bounds__(256) void k_tension(
    const float* __restrict__ outp, float* __restrict__ tens)
{
  int m = blockIdx.x, t = threadIdx.x;
  float s = 0.0f;
  for (int j=t;j<OD;j+=256){ float v = outp[(size_t)m*OD + j]; s += v*v; }
  __shared__ float red[256];
  red[t]=s; __syncthreads();
  for(int k=128;k>0;k>>=1){ if(t<k) red[t]+=red[t+k]; __syncthreads(); }
  if (t==0) tens[m] = red[0] * (1.0f/OD);
}

// ---------------------------------------------------------------------------
// GRU elementwise combine: newh = (1-z)*nn + z*h
__global__ __launch_bounds__(256) void k_gru_elem(
    const unsigned short* __restrict__ gi, const unsigned short* __restrict__ gh,
    const float* __restrict__ h, const float* __restrict__ bhh,
    float* __restrict__ newh)
{
  size_t idx = (size_t)blockIdx.x*256 + threadIdx.x;   // NC*HD
  int n = (int)(idx & (HD-1));
  size_t m = idx >> 10;
  size_t b = m*(3*HD) + n;
  float i_r = bf2f(gi[b]), i_z = bf2f(gi[b+HD]), i_n = bf2f(gi[b+2*HD]);
  float h_r = bf2f(gh[b]), h_z = bf2f(gh[b+HD]), h_n = bf2f(gh[b+2*HD]);
  float r  = sigmf(i_r + h_r + bhh[n]);
  float z  = sigmf(i_z + h_z + bhh[HD+n]);
  float nn = tanhf(i_n + r*(h_n + bhh[2*HD+n]));
  newh[idx] = (1.0f-z)*nn + z*h[idx];
}

// ---------------------------------------------------------------------------
__global__ __launch_bounds__(256) void k_fmean(
    const float* __restrict__ newh, float* __restrict__ fmean)
{
  int f = blockIdx.x;
  int j = blockIdx.y*256 + threadIdx.x;
  const float* base = newh + (size_t)f*FS*HD + j;
  float s = 0.0f;
  for (int c=0;c<FS;c++) s += base[(size_t)c*HD];
  fmean[f*HD + j] = s * (1.0f/FS);
}

__global__ __launch_bounds__(256) void k_sync(
    float* __restrict__ newh, const float* __restrict__ fmean,
    const int* __restrict__ step)
{
  size_t idx = (size_t)blockIdx.x*256 + threadIdx.x;
  int cell = (int)(idx / HD);
  int j    = (int)(idx % HD);
  int f = cell / FS, c = cell % FS;
  float v = newh[idx];
  v = 0.85f*v + 0.15f*fmean[f*HD + j];
  if (step[0] > 5 && c < DC){
    float glob = 0.0f;
    for (int ff=0; ff<NF; ff++) glob += fmean[ff*HD + j];
    glob *= (1.0f/NF);
    v = 0.85f*v + 0.15f*glob;
  }
  newh[idx] = v;
}

__global__ __launch_bounds__(1024) void k_wstats(
    const float* __restrict__ tens, float* __restrict__ stats)
{
  int t = threadIdx.x;
  float mx = -1e30f;
  for (int i=t;i<NC;i+=1024) mx = fmaxf(mx, tens[i]);
  __shared__ float red[1024];
  red[t]=mx; __syncthreads();
  for(int s=512;s>0;s>>=1){ if(t<s) red[t]=fmaxf(red[t],red[t+s]); __syncthreads(); }
  mx = red[0]; __syncthreads();
  float sm=0.0f;
  for (int i=t;i<NC;i+=1024) sm += __expf(tens[i]-mx);
  red[t]=sm; __syncthreads();
  for(int s=512;s>0;s>>=1){ if(t<s) red[t]+=red[t+s]; __syncthreads(); }
  if (t==0){ stats[0]=mx; stats[1]=red[0]; }
}

__global__ __launch_bounds__(256) void k_wnorm(
    const float* __restrict__ tens, const float* __restrict__ stats,
    float* __restrict__ w)
{
  int m = blockIdx.x*256 + threadIdx.x;
  w[m] = __expf(tens[m]-stats[0]) * (1.0f/stats[1]);
}

__global__ __launch_bounds__(256) void k_combined(
    const float* __restrict__ outp, const float* __restrict__ w,
    float* __restrict__ comb)
{
  int n = blockIdx.x, t = threadIdx.x;
  float s = 0.0f;
  for (int m=t; m<NC; m+=256) s += w[m]*outp[(size_t)m*OD + n];
  __shared__ float red[256];
  red[t]=s; __syncthreads();
  for (int sx=128;sx>0;sx>>=1){ if(t<sx) red[t]+=red[t+sx]; __syncthreads(); }
  if (t==0) comb[n] = red[0];
}

__global__ __launch_bounds__(128) void k_pred(
    const float* __restrict__ comb, const float* __restrict__ headW,
    const float* __restrict__ headb, float* __restrict__ pred)
{
  int i = blockIdx.x, t = threadIdx.x;
  float s = 0.0f;
  const float* wr = headW + (size_t)i*OD;
  for (int k=t;k<OD;k+=128) s += comb[k]*wr[k];
  __shared__ float red[128];
  red[t]=s; __syncthreads();
  for (int sx=64;sx>0;sx>>=1){ if(t<sx) red[t]+=red[t+sx]; __syncthreads(); }
  if (t==0) pred[i] = red[0] + headb[i];
}

// ---------------------------------------------------------------------------
extern "C" void kernel_launch(void* const* d_in, const int* in_sizes, int n_in,
                              void* d_out, int out_size, void* d_ws, size_t ws_size,
                              hipStream_t stream)
{
  const float* x        = (const float*)d_in[0];
  const float* rho_diag = (const float*)d_in[1];
  const float* rho_off  = (const float*)d_in[2];
  const float* hiddens  = (const float*)d_in[3];
  const float* gamma    = (const float*)d_in[4];
  const float* proj_W   = (const float*)d_in[5];
  const float* proj_b   = (const float*)d_in[6];
  const float* a_W1     = (const float*)d_in[7];
  const float* a_b1     = (const float*)d_in[8];
  const float* a_W2     = (const float*)d_in[9];
  const float* a_b2     = (const float*)d_in[10];
  const float* g_W1     = (const float*)d_in[11];
  const float* g_b1     = (const float*)d_in[12];
  const float* g_W2     = (const float*)d_in[13];
  const float* g_b2     = (const float*)d_in[14];
  const float* gru_Wih  = (const float*)d_in[15];
  const float* gru_bih  = (const float*)d_in[16];
  const float* gru_Whh  = (const float*)d_in[17];
  const float* gru_bhh  = (const float*)d_in[18];
  const float* head_W   = (const float*)d_in[19];
  const float* head_b   = (const float*)d_in[20];
  const float* noise_d  = (const float*)d_in[21];
  const int*   step     = (const int*)d_in[23];

  float* pred = (float*)d_out;                  // [512]
  float* newh = (float*)d_out + ID;             // [NC*HD]

  char* ws = (char*)d_ws;
  const size_t MB = 1024*1024;
  unsigned short* gi_b   = (unsigned short*)(ws + 0);        // [NC][3072] 48MB
  unsigned short* featb  = (unsigned short*)(ws + 0);        // [NC][2048] 32MB (dead before gi)
  unsigned short* gh_b   = (unsigned short*)(ws + 48*MB);    // [NC][3072] 48MB
  float*          h_f    = (float*)(ws + 96*MB);             // [NC][HD]  32MB
  unsigned short* h_b    = (unsigned short*)(ws + 128*MB);   // [NC][HD]  16MB
  float*          outp_f = (float*)(ws + 144*MB);            // [NC][OD]  16MB
  unsigned short* outp_b = (unsigned short*)(ws + 160*MB);   // [NC][OD]   8MB
  unsigned short* eag    = (unsigned short*)(ws + 168*MB);   // [NC][256]  4MB
  unsigned short* wProj  = (unsigned short*)(ws + 172*MB);   // [1024][2048] 4MB
  unsigned short* wWhh   = (unsigned short*)(ws + 176*MB);   // [3072][1024] 6MB
  unsigned short* wWih   = (unsigned short*)(ws + 182*MB);   // [3072][512]  3MB
  unsigned short* wEng   = (unsigned short*)(ws + 185*MB);   // [256][1024] 0.5MB
  unsigned short* wW2    = (unsigned short*)(ws + 185*MB + 512*1024); // [512][256] 0.25MB
  char* sm = ws + 186*MB;
  float* tens   = (float*)(sm + 0);         // [NC]
  float* xcat   = (float*)(sm + 64*1024);   // [256]
  float* wlast  = (float*)(sm + 128*1024);  // [3HD]
  float* b2diff = (float*)(sm + 160*1024);  // [OD]
  float* fmean  = (float*)(sm + 192*1024);  // [NF*HD]
  float* stats  = (float*)(sm + 256*1024);  // [2]
  float* wts    = (float*)(sm + 320*1024);  // [NC]
  float* comb   = (float*)(sm + 384*1024);  // [OD]

  dim3 blk(256);
  #define CONVGRID(n) dim3(((n)/4 + 255)/256)

  // weight conversions
  k_conv<<<CONVGRID(1024*2048), blk, 0, stream>>>(proj_W,  wProj, 1024, 2048, 2048, 0, 2048, 1.0f);
  k_conv<<<CONVGRID(3072*1024), blk, 0, stream>>>(gru_Whh, wWhh,  3072, 1024, 1024, 0, 1024, 1.0f);
  k_conv<<<CONVGRID(3072*512),  blk, 0, stream>>>(gru_Wih, wWih,  3072, 512,  513,  0, 512,  1.0f);
  k_conv<<<CONVGRID(128*1024),  blk, 0, stream>>>(a_W1, wEng,            128, 1024, ID+HD, ID, 1024, 1.0f);
  k_conv<<<CONVGRID(128*1024),  blk, 0, stream>>>(g_W1, wEng + 128*1024, 128, 1024, ID+HD, ID, 1024, 1.0f);
  k_conv<<<CONVGRID(512*128),   blk, 0, stream>>>(a_W2, wW2,       512, 128, 128, 0, 256,  1.0f);
  k_conv<<<CONVGRID(512*128),   blk, 0, stream>>>(g_W2, wW2 + 128, 512, 128, 128, 0, 256, -1.0f);

  // feat + x-part
  k_feat<<<dim3(NC), blk, 0, stream>>>(rho_diag, noise_d, rho_off, gamma, featb);
  k_xpart<<<dim3(3), dim3(128), 0, stream>>>(x, a_W1, a_b1, g_W1, g_b1, gru_Wih,
                                             a_b2, g_b2, xcat, wlast, b2diff);

  // inj: h = hiddens + 0.1*(feat@projW^T + b)
  k_mgemm<0><<<dim3(HD/128, NC/128), blk, 0, stream>>>(
      featb, wProj, 2*HD, HD, h_f, h_b, HD, hiddens, proj_b, nullptr);
  // engine hidden: eag = relu(h@W1h^T + xcat)
  k_mgemm<1><<<dim3(256/128, NC/128), blk, 0, stream>>>(
      h_b, wEng, HD, 256, nullptr, eag, 256, xcat, nullptr, nullptr);
  // out = eag@W2cat^T + (ab2-gb2)
  k_mgemm<2><<<dim3(OD/128, NC/128), blk, 0, stream>>>(
      eag, wW2, 256, OD, outp_f, outp_b, OD, b2diff, nullptr, nullptr);
  // tension
  k_tension<<<dim3(NC), blk, 0, stream>>>(outp_f, tens);
  // gi = out@Wih^T + bih + tens*wlast
  k_mgemm<4><<<dim3(3*HD/128, NC/128), blk, 0, stream>>>(
      outp_b, wWih, OD, 3*HD, nullptr, gi_b, 3*HD, gru_bih, tens, wlast);
  // gh = h@Whh^T
  k_mgemm<3><<<dim3(3*HD/128, NC/128), blk, 0, stream>>>(
      h_b, wWhh, HD, 3*HD, nullptr, gh_b, 3*HD, nullptr, nullptr, nullptr);
  // GRU combine
  k_gru_elem<<<dim3((NC*HD)/256), blk, 0, stream>>>(gi_b, gh_b, h_f, gru_bhh, newh);
  // faction sync
  k_fmean<<<dim3(NF, HD/256), blk, 0, stream>>>(newh, fmean);
  k_sync<<<dim3((NC*HD)/256), blk, 0, stream>>>(newh, fmean, step);
  // tension softmax -> combined -> pred
  k_wstats<<<dim3(1), dim3(1024), 0, stream>>>(tens, stats);
  k_wnorm<<<dim3(NC/256), blk, 0, stream>>>(tens, stats, wts);
  k_combined<<<dim3(OD), blk, 0, stream>>>(outp_f, wts, comb);
  k_pred<<<dim3(ID), dim3(128), 0, stream>>>(comb, head_W, head_b, pred);
}

// Round 5
// 602.758 us; speedup vs baseline: 5.4743x; 1.0345x over previous
//
#include <hip/hip_runtime.h>
#include <math.h>

#define NC 8192
#define ID 512
#define HD 1024
#define OD 512
#define ED 128
#define NF 8
#define FS (NC/NF)   /* 1024 */
#define DC (FS/4)    /* 256 */

typedef __bf16 bf16x8 __attribute__((ext_vector_type(8)));
typedef float  f32x4  __attribute__((ext_vector_type(4)));

__device__ __forceinline__ float sigmf(float x){ return 1.0f/(1.0f+__expf(-x)); }

__device__ __forceinline__ unsigned short f2bf(float f){
  union { float f; unsigned u; } v; v.f = f;
  unsigned r = v.u + 0x7FFFu + ((v.u >> 16) & 1u);
  return (unsigned short)(r >> 16);
}
__device__ __forceinline__ float bf2f(unsigned short b){
  union { unsigned u; float f; } v; v.u = ((unsigned)b) << 16;
  return v.f;
}
__device__ __forceinline__ void gload16(const void* g, void* l){
  __builtin_amdgcn_global_load_lds(
      (const __attribute__((address_space(1))) unsigned int*)g,
      (__attribute__((address_space(3))) unsigned int*)l, 16, 0, 0);
}

// ---------------------------------------------------------------------------
// weight fp32 -> bf16 strided converter
__global__ __launch_bounds__(256) void k_conv(
    const float* __restrict__ src, unsigned short* __restrict__ dst,
    int rows, int cols, int sld, int sofs, int dld, float scale)
{
  int i = blockIdx.x*256 + threadIdx.x;
  int total = rows*cols/4;
  if (i >= total) return;
  int r = (i*4)/cols, c = (i*4)%cols;
  const float* s = src + (size_t)r*sld + sofs + c;
  unsigned long long pack = 0;
  for (int q=0;q<4;q++)
    pack |= (unsigned long long)f2bf(s[q]*scale) << (16*q);
  *reinterpret_cast<unsigned long long*>(&dst[(size_t)r*dld + c]) = pack;
}

// gate-cat GRU weights: dst[3][1024][1536] = [Wih_gate(512) | Whh_gate(1024)]
__global__ __launch_bounds__(256) void k_convgru(
    const float* __restrict__ Wih, const float* __restrict__ Whh,
    unsigned short* __restrict__ dst)
{
  int i = blockIdx.x*256 + threadIdx.x;         // group of 4
  const int total = 3*1024*1536/4;
  if (i >= total) return;
  int row = (i*4)/1536, c = (i*4)%1536;         // row = g*1024+n
  unsigned long long pack = 0;
  if (c < 512){
    const float* s = Wih + (size_t)row*(OD+1) + c;
    for (int q=0;q<4;q++) pack |= (unsigned long long)f2bf(s[q]) << (16*q);
  } else {
    const float* s = Whh + (size_t)row*HD + (c-512);
    for (int q=0;q<4;q++) pack |= (unsigned long long)f2bf(s[q]) << (16*q);
  }
  *reinterpret_cast<unsigned long long*>(&dst[(size_t)row*1536 + c]) = pack;
}

// ---------------------------------------------------------------------------
// K1: decohere features -> bf16 feat[NC][2HD]
__global__ __launch_bounds__(256) void k_feat(
    const float* __restrict__ rho_diag, const float* __restrict__ noise_diag,
    const float* __restrict__ rho_off,  const float* __restrict__ gamma,
    unsigned short* __restrict__ featb)
{
  int row = blockIdx.x;
  int t = threadIdx.x;
  float g = 1.0f/(1.0f+__expf(-gamma[0]));
  const float* rd = rho_diag  + (size_t)row*HD;
  const float* nd = noise_diag+ (size_t)row*HD;
  const float* ro = rho_off   + (size_t)row*HD;
  unsigned short* f0 = featb + (size_t)row*(2*HD);

  float v[4];
  float mx = -1e30f;
  for (int i=0;i<4;i++){ int j=t+i*256; v[i] = rd[j] + nd[j]*g*0.1f; mx = fmaxf(mx, v[i]); }
  __shared__ float red[256];
  red[t]=mx; __syncthreads();
  for(int s=128;s>0;s>>=1){ if(t<s) red[t]=fmaxf(red[t],red[t+s]); __syncthreads(); }
  mx = red[0]; __syncthreads();
  float sm=0.0f;
  for(int i=0;i<4;i++){ v[i]=__expf(v[i]-mx); sm+=v[i]; }
  red[t]=sm; __syncthreads();
  for(int s=128;s>0;s>>=1){ if(t<s) red[t]+=red[t+s]; __syncthreads(); }
  float inv = 1.0f/red[0];
  float om_g = 1.0f - g;
  for(int i=0;i<4;i++){
    int j=t+i*256;
    f0[j]     = f2bf(v[i]*inv);
    f0[HD+j]  = f2bf(fabsf(ro[j])*om_g);
  }
}

// ---------------------------------------------------------------------------
// MFMA bf16 GEMM: C[M,N] = A[M,K] @ W[N,K]^T, 128x128 tile, BK=32, 4 waves.
// MODE 0: v = e0[m*N+n] + 0.1*(acc + e1[n]); write Cb only     (inj -> h bf16)
// MODE 1: v = relu(acc + e0[n]);            write Cb only      (engine hidden)
// MODE 2: v = acc + e0[n];                  write Cf + Cb      (out)
template<int MODE>
__global__ __launch_bounds__(256) void k_mgemm(
    const unsigned short* __restrict__ A, int lda,
    const unsigned short* __restrict__ W,
    int K, int N,
    float* __restrict__ Cf, int ldcf,
    unsigned short* __restrict__ Cb, int ldcb,
    const float* __restrict__ e0, const float* __restrict__ e1)
{
  __shared__ __attribute__((aligned(16))) unsigned short Asb[128*32];
  __shared__ __attribute__((aligned(16))) unsigned short Bsb[128*32];
  const int t = threadIdx.x;
  const int lane = t & 63, wid = t >> 6;
  const int wr = wid >> 1, wc = wid & 1;

  // XCD chunked swizzle (all grids have nwg % 8 == 0)
  const int nwg = gridDim.x*gridDim.y;
  const int bid = blockIdx.y*gridDim.x + blockIdx.x;
  const int swz = (bid & 7)*(nwg >> 3) + (bid >> 3);
  const int m0 = (swz / gridDim.x) * 128, n0 = (swz % gridDim.x) * 128;

  const int srow = lane >> 2;
  const int skch = (lane & 3) * 8;
  const int fr = lane & 15, fk = (lane >> 4) * 8;

  f32x4 acc[4][4] = {};
  for (int k0 = 0; k0 < K; k0 += 32) {
    for (int q = 0; q < 2; ++q) {
      int r = wid*32 + q*16 + srow;
      gload16(A + (size_t)(m0 + r)*lda + k0 + skch, &Asb[(wid*32 + q*16)*32]);
      gload16(W + (size_t)(n0 + r)*K   + k0 + skch, &Bsb[(wid*32 + q*16)*32]);
    }
    __syncthreads();
    bf16x8 af[4], bfr[4];
    for (int i = 0; i < 4; ++i)
      af[i]  = *reinterpret_cast<const bf16x8*>(&Asb[(wr*64 + i*16 + fr)*32 + fk]);
    for (int j = 0; j < 4; ++j)
      bfr[j] = *reinterpret_cast<const bf16x8*>(&Bsb[(wc*64 + j*16 + fr)*32 + fk]);
    for (int i = 0; i < 4; ++i)
      for (int j = 0; j < 4; ++j)
        acc[i][j] = __builtin_amdgcn_mfma_f32_16x16x32_bf16(af[i], bfr[j], acc[i][j], 0, 0, 0);
    __syncthreads();
  }
  const int cr = (lane >> 4) * 4;
  const int cc = lane & 15;
  for (int i = 0; i < 4; ++i){
    for (int j = 0; j < 4; ++j){
      for (int r = 0; r < 4; ++r){
        int m = m0 + wr*64 + i*16 + cr + r;
        int n = n0 + wc*64 + j*16 + cc;
        float v = acc[i][j][r];
        if (MODE == 0)      v = e0[(size_t)m*N + n] + 0.1f*(v + e1[n]);
        else if (MODE == 1) v = fmaxf(v + e0[n], 0.0f);
        else if (MODE == 2) v = v + e0[n];
        if (MODE == 2) Cf[(size_t)m*ldcf + n] = v;
        Cb[(size_t)m*ldcb + n] = f2bf(v);
      }
    }
  }
}

// ---------------------------------------------------------------------------
// GRU megakernel: Acat[NC][1536] = [out(512) | h(1024)] bf16.
// Per 64x64 tile of (m, n<1024): computes
//   r  = sigm( out@WihR + h@WhhR + bih[n]   + tens*wlast[n]    + bhh[n] )
//   z  = sigm( out@WihZ + h@WhhZ + bih[H+n] + tens*wlast[H+n]  + bhh[H+n] )
//   nn = tanh( out@WihN + bih[2H+n] + tens*wlast[2H+n] + r*(h@WhhN + bhh[2H+n]) )
//   newh = (1-z)*nn + z*h
__global__ __launch_bounds__(256) void k_gru_mega(
    const unsigned short* __restrict__ Acat,
    const unsigned short* __restrict__ Wg,   // [3][1024][1536] gate-cat
    const float* __restrict__ bih, const float* __restrict__ bhh,
    const float* __restrict__ tens, const float* __restrict__ wlast,
    float* __restrict__ newh)
{
  __shared__ __attribute__((aligned(16))) unsigned short As[64*32];
  __shared__ __attribute__((aligned(16))) unsigned short Rs[64*32];
  __shared__ __attribute__((aligned(16))) unsigned short Zs[64*32];
  __shared__ __attribute__((aligned(16))) unsigned short Ns[64*32];
  const int t = threadIdx.x;
  const int lane = t & 63, wid = t >> 6;
  const int wr = wid >> 1, wc = wid & 1;

  const int nwg = gridDim.x*gridDim.y;     // (16, 128) = 2048
  const int bid = blockIdx.y*gridDim.x + blockIdx.x;
  const int swz = (bid & 7)*(nwg >> 3) + (bid >> 3);
  const int m0 = (swz >> 4) * 64, n0 = (swz & 15) * 64;

  const int srow = lane >> 2;          // 0..15
  const int skch = (lane & 3) * 8;
  const int fr = lane & 15, fk = (lane >> 4) * 8;

  // wave w stages matrix w (A, Wr, Wz, Wn): 4 gload16 of 16 rows each
  const unsigned short* sbase;
  unsigned short* lbase;
  if      (wid == 0){ sbase = Acat + (size_t)m0*1536;              lbase = As; }
  else if (wid == 1){ sbase = Wg   + (size_t)n0*1536;              lbase = Rs; }
  else if (wid == 2){ sbase = Wg + (size_t)(HD + n0)*1536;         lbase = Zs; }
  else              { sbase = Wg + (size_t)(2*HD + n0)*1536;       lbase = Ns; }

  f32x4 acc_r[2][2] = {}, acc_z[2][2] = {}, acc_na[2][2] = {}, acc_nb[2][2] = {};

  for (int k0 = 0; k0 < 1536; k0 += 32) {
    for (int q = 0; q < 4; ++q)
      gload16(sbase + (size_t)(q*16 + srow)*1536 + k0 + skch, &lbase[(q*16)*32]);
    __syncthreads();
    bf16x8 af[2], br[2], bz[2], bn[2];
    for (int i = 0; i < 2; ++i)
      af[i] = *reinterpret_cast<const bf16x8*>(&As[(wr*32 + i*16 + fr)*32 + fk]);
    for (int j = 0; j < 2; ++j){
      br[j] = *reinterpret_cast<const bf16x8*>(&Rs[(wc*32 + j*16 + fr)*32 + fk]);
      bz[j] = *reinterpret_cast<const bf16x8*>(&Zs[(wc*32 + j*16 + fr)*32 + fk]);
      bn[j] = *reinterpret_cast<const bf16x8*>(&Ns[(wc*32 + j*16 + fr)*32 + fk]);
    }
    if (k0 < 512){
      for (int i = 0; i < 2; ++i)
        for (int j = 0; j < 2; ++j){
          acc_r [i][j] = __builtin_amdgcn_mfma_f32_16x16x32_bf16(af[i], br[j], acc_r [i][j], 0,0,0);
          acc_z [i][j] = __builtin_amdgcn_mfma_f32_16x16x32_bf16(af[i], bz[j], acc_z [i][j], 0,0,0);
          acc_na[i][j] = __builtin_amdgcn_mfma_f32_16x16x32_bf16(af[i], bn[j], acc_na[i][j], 0,0,0);
        }
    } else {
      for (int i = 0; i < 2; ++i)
        for (int j = 0; j < 2; ++j){
          acc_r [i][j] = __builtin_amdgcn_mfma_f32_16x16x32_bf16(af[i], br[j], acc_r [i][j], 0,0,0);
          acc_z [i][j] = __builtin_amdgcn_mfma_f32_16x16x32_bf16(af[i], bz[j], acc_z [i][j], 0,0,0);
          acc_nb[i][j] = __builtin_amdgcn_mfma_f32_16x16x32_bf16(af[i], bn[j], acc_nb[i][j], 0,0,0);
        }
    }
    __syncthreads();
  }

  const int cr = (lane >> 4) * 4;
  const int cc = lane & 15;
  for (int i = 0; i < 2; ++i){
    for (int r = 0; r < 4; ++r){
      int m = m0 + wr*32 + i*16 + cr + r;
      float tm = tens[m];
      for (int j = 0; j < 2; ++j){
        int n = n0 + wc*32 + j*16 + cc;
        float sr  = acc_r [i][j][r] + bih[n]      + tm*wlast[n]      + bhh[n];
        float sz  = acc_z [i][j][r] + bih[HD+n]   + tm*wlast[HD+n]   + bhh[HD+n];
        float sni = acc_na[i][j][r] + bih[2*HD+n] + tm*wlast[2*HD+n];
        float snh = acc_nb[i][j][r] + bhh[2*HD+n];
        float rg = sigmf(sr);
        float zg = sigmf(sz);
        float nn = tanhf(sni + rg*snh);
        float hv = bf2f(Acat[(size_t)m*1536 + 512 + n]);
        newh[(size_t)m*HD + n] = (1.0f - zg)*nn + zg*hv;
      }
    }
  }
}

// ---------------------------------------------------------------------------
__global__ __launch_bounds__(128) void k_xpart(
    const float* __restrict__ x,
    const float* __restrict__ aW1, const float* __restrict__ ab1,
    const float* __restrict__ gW1, const float* __restrict__ gb1,
    const float* __restrict__ Wih,
    const float* __restrict__ ab2, const float* __restrict__ gb2,
    float* __restrict__ xcat, float* __restrict__ wlast, float* __restrict__ b2diff)
{
  int t = threadIdx.x;
  if (blockIdx.x == 2){
    for (int n=t; n<3*HD; n+=128) wlast[n] = Wih[(size_t)n*(OD+1) + OD];
    for (int n=t; n<OD;   n+=128) b2diff[n] = ab2[n] - gb2[n];
    return;
  }
  const float* W = blockIdx.x ? gW1 : aW1;
  const float* b = blockIdx.x ? gb1 : ab1;
  float s = b[t];
  const float* wr = W + (size_t)t*(ID+HD);
  for (int k=0;k<ID;k++) s += x[k]*wr[k];
  xcat[blockIdx.x*ED + t] = s;
}

// ---------------------------------------------------------------------------
__global__ __launch_bounds__(256) void k_tension(
    const float* __restrict__ outp, float* __restrict__ tens)
{
  int m = blockIdx.x, t = threadIdx.x;
  float s = 0.0f;
  for (int j=t;j<OD;j+=256){ float v = outp[(size_t)m*OD + j]; s += v*v; }
  __shared__ float red[256];
  red[t]=s; __syncthreads();
  for(int k=128;k>0;k>>=1){ if(t<k) red[t]+=red[t+k]; __syncthreads(); }
  if (t==0) tens[m] = red[0] * (1.0f/OD);
}

// ---------------------------------------------------------------------------
__global__ __launch_bounds__(256) void k_fmean(
    const float* __restrict__ newh, float* __restrict__ fmean)
{
  int f = blockIdx.x;
  int j = blockIdx.y*256 + threadIdx.x;
  const float* base = newh + (size_t)f*FS*HD + j;
  float s = 0.0f;
  for (int c=0;c<FS;c++) s += base[(size_t)c*HD];
  fmean[f*HD + j] = s * (1.0f/FS);
}

__global__ __launch_bounds__(256) void k_sync(
    float* __restrict__ newh, const float* __restrict__ fmean,
    const int* __restrict__ step)
{
  size_t idx = (size_t)blockIdx.x*256 + threadIdx.x;
  int cell = (int)(idx / HD);
  int j    = (int)(idx % HD);
  int f = cell / FS, c = cell % FS;
  float v = newh[idx];
  v = 0.85f*v + 0.15f*fmean[f*HD + j];
  if (step[0] > 5 && c < DC){
    float glob = 0.0f;
    for (int ff=0; ff<NF; ff++) glob += fmean[ff*HD + j];
    glob *= (1.0f/NF);
    v = 0.85f*v + 0.15f*glob;
  }
  newh[idx] = v;
}

__global__ __launch_bounds__(1024) void k_wstats(
    const float* __restrict__ tens, float* __restrict__ stats)
{
  int t = threadIdx.x;
  float mx = -1e30f;
  for (int i=t;i<NC;i+=1024) mx = fmaxf(mx, tens[i]);
  __shared__ float red[1024];
  red[t]=mx; __syncthreads();
  for(int s=512;s>0;s>>=1){ if(t<s) red[t]=fmaxf(red[t],red[t+s]); __syncthreads(); }
  mx = red[0]; __syncthreads();
  float sm=0.0f;
  for (int i=t;i<NC;i+=1024) sm += __expf(tens[i]-mx);
  red[t]=sm; __syncthreads();
  for(int s=512;s>0;s>>=1){ if(t<s) red[t]+=red[t+s]; __syncthreads(); }
  if (t==0){ stats[0]=mx; stats[1]=red[0]; }
}

__global__ __launch_bounds__(256) void k_wnorm(
    const float* __restrict__ tens, const float* __restrict__ stats,
    float* __restrict__ w)
{
  int m = blockIdx.x*256 + threadIdx.x;
  w[m] = __expf(tens[m]-stats[0]) * (1.0f/stats[1]);
}

// combined stage 1: 64 blocks, each sums 128 rows (coalesced), writes partial[b][512]
__global__ __launch_bounds__(256) void k_comb1(
    const float* __restrict__ outp, const float* __restrict__ w,
    float* __restrict__ partial)
{
  int b = blockIdx.x, t = threadIdx.x;
  float a0 = 0.0f, a1 = 0.0f;
  for (int m = 0; m < 128; ++m){
    int row = b*128 + m;
    float wm = w[row];
    const float* r = outp + (size_t)row*OD;
    a0 += wm * r[t];
    a1 += wm * r[t+256];
  }
  partial[(size_t)b*OD + t]       = a0;
  partial[(size_t)b*OD + t + 256] = a1;
}

// combined stage 2: comb[n] = sum_b partial[b][n]
__global__ __launch_bounds__(256) void k_comb2(
    const float* __restrict__ partial, float* __restrict__ comb)
{
  int n = blockIdx.x*256 + threadIdx.x;
  float s = 0.0f;
  for (int b = 0; b < 64; ++b) s += partial[(size_t)b*OD + n];
  comb[n] = s;
}

__global__ __launch_bounds__(128) void k_pred(
    const float* __restrict__ comb, const float* __restrict__ headW,
    const float* __restrict__ headb, float* __restrict__ pred)
{
  int i = blockIdx.x, t = threadIdx.x;
  float s = 0.0f;
  const float* wr = headW + (size_t)i*OD;
  for (int k=t;k<OD;k+=128) s += comb[k]*wr[k];
  __shared__ float red[128];
  red[t]=s; __syncthreads();
  for (int sx=64;sx>0;sx>>=1){ if(t<sx) red[t]+=red[t+sx]; __syncthreads(); }
  if (t==0) pred[i] = red[0] + headb[i];
}

// ---------------------------------------------------------------------------
extern "C" void kernel_launch(void* const* d_in, const int* in_sizes, int n_in,
                              void* d_out, int out_size, void* d_ws, size_t ws_size,
                              hipStream_t stream)
{
  const float* x        = (const float*)d_in[0];
  const float* rho_diag = (const float*)d_in[1];
  const float* rho_off  = (const float*)d_in[2];
  const float* hiddens  = (const float*)d_in[3];
  const float* gamma    = (const float*)d_in[4];
  const float* proj_W   = (const float*)d_in[5];
  const float* proj_b   = (const float*)d_in[6];
  const float* a_W1     = (const float*)d_in[7];
  const float* a_b1     = (const float*)d_in[8];
  const float* a_W2     = (const float*)d_in[9];
  const float* a_b2     = (const float*)d_in[10];
  const float* g_W1     = (const float*)d_in[11];
  const float* g_b1     = (const float*)d_in[12];
  const float* g_W2     = (const float*)d_in[13];
  const float* g_b2     = (const float*)d_in[14];
  const float* gru_Wih  = (const float*)d_in[15];
  const float* gru_bih  = (const float*)d_in[16];
  const float* gru_Whh  = (const float*)d_in[17];
  const float* gru_bhh  = (const float*)d_in[18];
  const float* head_W   = (const float*)d_in[19];
  const float* head_b   = (const float*)d_in[20];
  const float* noise_d  = (const float*)d_in[21];
  const int*   step     = (const int*)d_in[23];

  float* pred = (float*)d_out;                  // [512]
  float* newh = (float*)d_out + ID;             // [NC*HD]

  char* ws = (char*)d_ws;
  const size_t MB = 1024*1024;
  unsigned short* Acat   = (unsigned short*)(ws + 0);        // [NC][1536] 24MB
  unsigned short* featb  = (unsigned short*)(ws + 24*MB);    // [NC][2048] 32MB
  float*          outp_f = (float*)(ws + 56*MB);             // [NC][512] 16MB
  unsigned short* eag    = (unsigned short*)(ws + 72*MB);    // [NC][256]  4MB
  unsigned short* wProj  = (unsigned short*)(ws + 76*MB);    // [1024][2048] 4MB
  unsigned short* wGru   = (unsigned short*)(ws + 80*MB);    // [3][1024][1536] 9MB
  unsigned short* wEng   = (unsigned short*)(ws + 89*MB);    // [256][1024] 0.5MB
  unsigned short* wW2    = (unsigned short*)(ws + 89*MB + 512*1024); // [512][256] 0.25MB
  char* sm = ws + 90*MB;
  float* tens    = (float*)(sm + 0);          // [NC]
  float* xcat    = (float*)(sm + 64*1024);    // [256]
  float* wlast   = (float*)(sm + 128*1024);   // [3HD]
  float* b2diff  = (float*)(sm + 160*1024);   // [OD]
  float* fmean   = (float*)(sm + 192*1024);   // [NF*HD]
  float* stats   = (float*)(sm + 256*1024);   // [2]
  float* wts     = (float*)(sm + 320*1024);   // [NC]
  float* partial = (float*)(sm + 384*1024);   // [64][512] 128KB
  float* comb    = (float*)(sm + 576*1024);   // [OD]

  dim3 blk(256);
  #define CONVGRID(n) dim3(((n)/4 + 255)/256)

  // weight conversions
  k_conv<<<CONVGRID(1024*2048), blk, 0, stream>>>(proj_W, wProj, 1024, 2048, 2048, 0, 2048, 1.0f);
  k_convgru<<<dim3(3*1024*1536/4/256), blk, 0, stream>>>(gru_Wih, gru_Whh, wGru);
  k_conv<<<CONVGRID(128*1024), blk, 0, stream>>>(a_W1, wEng,            128, 1024, ID+HD, ID, 1024, 1.0f);
  k_conv<<<CONVGRID(128*1024), blk, 0, stream>>>(g_W1, wEng + 128*1024, 128, 1024, ID+HD, ID, 1024, 1.0f);
  k_conv<<<CONVGRID(512*128),  blk, 0, stream>>>(a_W2, wW2,       512, 128, 128, 0, 256,  1.0f);
  k_conv<<<CONVGRID(512*128),  blk, 0, stream>>>(g_W2, wW2 + 128, 512, 128, 128, 0, 256, -1.0f);

  // feat + x-part
  k_feat<<<dim3(NC), blk, 0, stream>>>(rho_diag, noise_d, rho_off, gamma, featb);
  k_xpart<<<dim3(3), dim3(128), 0, stream>>>(x, a_W1, a_b1, g_W1, g_b1, gru_Wih,
                                             a_b2, g_b2, xcat, wlast, b2diff);

  // inj: h(bf16) = hiddens + 0.1*(feat@projW^T + b) -> Acat cols 512..1535
  k_mgemm<0><<<dim3(HD/128, NC/128), blk, 0, stream>>>(
      featb, 2*HD, wProj, 2*HD, HD, nullptr, 0, Acat + 512, 1536, hiddens, proj_b);
  // engine hidden: eag = relu(h@W1h^T + xcat)
  k_mgemm<1><<<dim3(256/128, NC/128), blk, 0, stream>>>(
      Acat + 512, 1536, wEng, HD, 256, nullptr, 0, eag, 256, xcat, nullptr);
  // out = eag@W2cat^T + (ab2-gb2) -> outp_f + Acat cols 0..511
  k_mgemm<2><<<dim3(OD/128, NC/128), blk, 0, stream>>>(
      eag, 256, wW2, 256, OD, outp_f, OD, Acat, 1536, b2diff, nullptr);
  // tension
  k_tension<<<dim3(NC), blk, 0, stream>>>(outp_f, tens);
  // fused gi+gh+GRU -> newh
  k_gru_mega<<<dim3(HD/64, NC/64), blk, 0, stream>>>(
      Acat, wGru, gru_bih, gru_bhh, tens, wlast, newh);
  // faction sync
  k_fmean<<<dim3(NF, HD/256), blk, 0, stream>>>(newh, fmean);
  k_sync<<<dim3((NC*HD)/256), blk, 0, stream>>>(newh, fmean, step);
  // tension softmax -> combined -> pred
  k_wstats<<<dim3(1), dim3(1024), 0, stream>>>(tens, stats);
  k_wnorm<<<dim3(NC/256), blk, 0, stream>>>(tens, stats, wts);
  k_comb1<<<dim3(64), blk, 0, stream>>>(outp_f, wts, partial);
  k_comb2<<<dim3(2), blk, 0, stream>>>(partial, comb);
  k_pred<<<dim3(ID), dim3(128), 0, stream>>>(comb, head_W, head_b, pred);
}